// Round 9
// baseline (194.031 us; speedup 1.0000x reference)
//
#include <hip/hip_runtime.h>
#include <hip/hip_bf16.h>

// MHA B=16 T=1024 C=384 H=6 D=64 — bf16 MFMA pipeline.
// R7: qkv_proj fuses x-conversion + computes all 6 heads per mat per m-tile
//     (x read once in f32; X-tile resident in LDS; W double-buffered).
// ws: wt[3][H][D][C] | wpb | qv[B,H,T,D] | kv[B,H,T,D] | vt[B,H,D,T] | at[M,C]
#define Hn 6
#define Tn 1024
#define Cn 384
#define Dn 64
#define Bn 16
#define Mn (Bn*Tn)
#define QSCALE 0.07362222f   // log2(e)/sqrt(384): folds softmax scale + exp2 conversion into wq

typedef __attribute__((ext_vector_type(8)))  short s16x8;
typedef __attribute__((ext_vector_type(16))) float f32x16;

__device__ __forceinline__ void gl_lds16(const void* g, void* l) {
  __builtin_amdgcn_global_load_lds(
      (const __attribute__((address_space(1))) unsigned int*)g,
      (__attribute__((address_space(3))) unsigned int*)l, 16, 0, 0);
}
__device__ __forceinline__ unsigned pk2f(float a, float b) {
  __hip_bfloat162 h = __float22bfloat162_rn(make_float2(a, b));
  union { __hip_bfloat162 h; unsigned u; } cv; cv.h = h; return cv.u;
}
__device__ __forceinline__ f32x16 mfma32(s16x8 a, s16x8 b, f32x16 c) {
  return __builtin_amdgcn_mfma_f32_32x32x16_bf16(a, b, c, 0, 0, 0);
}

// ---------- convert (weights only): w -> bf16 transposed [mat][h][d][c] (wq scaled); wp->bf16 ----
__global__ __launch_bounds__(256) void convert_w(
    const float* __restrict__ wq, const float* __restrict__ wk,
    const float* __restrict__ wv, const float* __restrict__ wp,
    __hip_bfloat16* __restrict__ wt, __hip_bfloat16* __restrict__ wpb)
{
  const int bid = blockIdx.x, t = threadIdx.x;
  if (bid < 18) {                       // weight transpose, one (mat,h) per block
    __shared__ float lt[64][65];
    const int mat = bid / Hn, hh = bid % Hn;
    const float* src = (mat == 0 ? wq : mat == 1 ? wk : wv) + (size_t)hh * (Cn*Dn);
    __hip_bfloat16* dst = wt + (size_t)mat * (Hn*Dn*Cn) + (size_t)hh * (Dn*Cn);
    const float sc = (mat == 0) ? QSCALE : 1.0f;
    for (int ct = 0; ct < 6; ++ct) {    // 6 c-tiles of 64
      __syncthreads();
      #pragma unroll
      for (int ps = 0; ps < 4; ++ps) {
        int idx = ps*256 + t;
        int cl = idx >> 4, s4 = idx & 15;
        float4 v = *reinterpret_cast<const float4*>(src + (size_t)(ct*64 + cl)*Dn + s4*4);
        lt[cl][s4*4+0] = v.x * sc; lt[cl][s4*4+1] = v.y * sc;
        lt[cl][s4*4+2] = v.z * sc; lt[cl][s4*4+3] = v.w * sc;
      }
      __syncthreads();
      const int dd = t >> 2, cq = t & 3;
      #pragma unroll
      for (int i = 0; i < 16; ++i)
        dst[(size_t)dd*Cn + ct*64 + cq*16 + i] = __float2bfloat16(lt[cq*16 + i][dd]);
    }
  } else {                              // wp copy -> bf16
    const size_t base = (size_t)(bid - 18) * 2048 + (size_t)t * 8;
    float4 a = *reinterpret_cast<const float4*>(wp + base);
    float4 b = *reinterpret_cast<const float4*>(wp + base + 4);
    uint4 r; r.x = pk2f(a.x,a.y); r.y = pk2f(a.z,a.w); r.z = pk2f(b.x,b.y); r.w = pk2f(b.z,b.w);
    *reinterpret_cast<uint4*>((char*)wpb + base*2) = r;
  }
}

// ---------- qkv projection: grid (Mn/64, 3); block = one mat, one 64-row m-tile, ALL 6 heads.
// X[64][384]bf16 resident in LDS (48KB, slot16 ^ row&7 within-row); W dbuf 2x8KB.
__global__ __launch_bounds__(256) void qkv_proj(
    const float* __restrict__ x, const __hip_bfloat16* __restrict__ wt,
    __hip_bfloat16* __restrict__ qo, __hip_bfloat16* __restrict__ ko,
    __hip_bfloat16* __restrict__ vto)
{
  __shared__ __align__(16) char sm[65536];  // Xs@0 48KB | Wbuf0@49152 | Wbuf1@57344
  const int t = threadIdx.x, lane = t & 63, w = t >> 6;
  const int hi = lane >> 5, nl = lane & 31;
  const int wr = w >> 1, wc = w & 1;
  const int m0 = blockIdx.x * 64;
  const int mat = blockIdx.y;
  const char* wbase = (const char*)(wt + (size_t)mat * (Hn*Dn*Cn));

  const int mrow = wr*32 + nl;
  const int nrow = wc*32 + nl;

  auto stageW = [&](int h, int s, int buf) {   // 8KB W-tile (64 d-rows x 64 k), pre-swizzled src
    const char* wtile = wbase + (size_t)h * (Dn*Cn*2);
    #pragma unroll
    for (int r = 0; r < 2; ++r) {
      const int off = w*2048 + r*1024 + lane*16;     // byte off in 8KB tile
      const int row = off >> 7, sl = (off >> 4) & 7; // tile row stride 128B
      const char* src = wtile + (size_t)row*768 + s*128 + ((sl ^ (row & 7)) * 16);
      gl_lds16(src, sm + 49152 + buf*8192 + w*2048 + r*1024);
    }
  };

  // W(h=0,s=0) prefetch first, then X conversion overlaps its latency
  stageW(0, 0, 0);
  #pragma unroll 4
  for (int p = 0; p < 24; ++p) {              // x f32 -> bf16, swizzled ds_write_b64
    const int idx = p*256 + t;                // 6144 float4 = 64 rows x 96
    const int row = idx / 96, c4 = idx % 96;
    const float4 v = *reinterpret_cast<const float4*>(x + (size_t)(m0 + row)*Cn + c4*4);
    const unsigned long long pr =
        ((unsigned long long)pk2f(v.z, v.w) << 32) | pk2f(v.x, v.y);
    const int slot = c4 >> 1;                 // 16B slot 0..47
    const int swz  = (slot & ~7) | ((slot ^ row) & 7);
    *reinterpret_cast<unsigned long long*>(sm + row*768 + swz*16 + (c4 & 1)*8) = pr;
  }
  __syncthreads();

  f32x16 acc = {};
  for (int h = 0; h < Hn; ++h) {
    #pragma unroll
    for (int s = 0; s < 6; ++s) {
      if (!(h == 5 && s == 5)) {
        const int nh = (s < 5) ? h : h + 1;
        const int ns = (s < 5) ? s + 1 : 0;
        stageW(nh, ns, (s + 1) & 1);
      }
      const int buf = s & 1;
      __builtin_amdgcn_s_setprio(1);
      #pragma unroll
      for (int kk = 0; kk < 4; ++kk) {
        s16x8 a = *reinterpret_cast<const s16x8*>(
            sm + mrow*768 + (s*8 + ((2*kk + hi) ^ (mrow & 7))) * 16);
        s16x8 bv = *reinterpret_cast<const s16x8*>(
            sm + 49152 + buf*8192 + nrow*128 + (((2*kk + hi) ^ (nrow & 7)) * 16));
        acc = mfma32(a, bv, acc);
      }
      __builtin_amdgcn_s_setprio(0);
      if (s == 5) {
        // C layout: col = nl, row = (r&3)+8*(r>>2)+4*hi  [m74/m101]
        const int d = wc*32 + nl;
        if (mat < 2) {
          __hip_bfloat16* op = (mat == 0) ? qo : ko;
          #pragma unroll
          for (int r = 0; r < 16; ++r) {
            const int ml = wr*32 + (r & 3) + 8*(r >> 2) + 4*hi;
            const int M = m0 + ml, bI = M >> 10, tl = M & 1023;
            op[(((size_t)bI*Hn + h)*Tn + tl)*Dn + d] = __float2bfloat16(acc[r]);
          }
        } else {                         // V transposed: vto[b,h,d,t]
          #pragma unroll
          for (int rq = 0; rq < 4; ++rq) {
            const int ml = wr*32 + 8*rq + 4*hi;
            const int M = m0 + ml, bI = M >> 10, tl = M & 1023;
            const unsigned u0 = pk2f(acc[rq*4+0], acc[rq*4+1]);
            const unsigned u1 = pk2f(acc[rq*4+2], acc[rq*4+3]);
            const unsigned long long v = ((unsigned long long)u1 << 32) | u0;
            *reinterpret_cast<unsigned long long*>(
                (char*)vto + ((((size_t)bI*Hn + h)*Dn + d)*Tn + tl)*2) = v;
          }
        }
        acc = {};
      }
      __syncthreads();
    }
  }
}

// ---------- attention: QB=128 (4 waves x 32q), KV tiles 64, dbuf, swapped QK^T, no max-sub ----------
// Block swizzle: bh = bx%96, qt = bx/96 -> the 8 qt-blocks of one (b,h) share an XCD (96%8==0).
__global__ __launch_bounds__(256) void attn_fwd(
    const __hip_bfloat16* __restrict__ qb, const __hip_bfloat16* __restrict__ kb,
    const __hip_bfloat16* __restrict__ vtb, __hip_bfloat16* __restrict__ ao)
{
  __shared__ __align__(16) char smem[32768];   // 2 x (K[64][64] | VT[64][64]), slot16 ^ (row&7)
  const int t = threadIdx.x, lane = t & 63, w = t >> 6;
  const int hi = lane >> 5, qm = lane & 31;
  const int l7 = lane & 7;
  const int bx = blockIdx.x;
  const int bh = bx % 96, qt = bx / 96;        // XCD-grouping swizzle
  const int b = bh / Hn, h = bh % Hn;

  const int qrow = qt*128 + w*32 + qm;
  const __hip_bfloat16* qrp = qb + ((size_t)bh*Tn + qrow)*Dn;
  s16x8 qf[4];
  #pragma unroll
  for (int hh = 0; hh < 4; ++hh)
    qf[hh] = *reinterpret_cast<const s16x8*>(qrp + hh*16 + hi*8);

  const size_t kbase = (size_t)bh * Tn * Dn;
  const size_t vbase = (size_t)bh * Dn * Tn;

  f32x16 oacc[2] = {};
  float lsum = 0.f;

  auto stage = [&](int bb, int kt) {
    #pragma unroll
    for (int c = 0; c < 4; ++c) {
      const int off = w*4096 + c*1024 + lane*16;
      const char* src;
      if (off < 8192) {
        const int row = off >> 7, sl = (off >> 4) & 7;
        src = (const char*)(kb + kbase + (size_t)(kt*64 + row)*Dn) + ((sl ^ (row & 7)) * 16);
      } else {
        const int o2 = off - 8192;
        const int row = o2 >> 7, sl = (o2 >> 4) & 7;
        src = (const char*)(vtb + vbase + (size_t)row*Tn + kt*64) + ((sl ^ (row & 7)) * 16);
      }
      gl_lds16(src, smem + bb + w*4096 + c*1024);
    }
  };

  auto compute = [&](int bb) {
    f32x16 sacc[2] = {};
    __builtin_amdgcn_s_setprio(1);
    #pragma unroll
    for (int ts = 0; ts < 2; ++ts) {
      const int srow = ts*32 + qm;
      #pragma unroll
      for (int hh = 0; hh < 4; ++hh) {
        s16x8 ka = *reinterpret_cast<const s16x8*>(
            smem + bb + srow*128 + (((2*hh + hi) ^ l7) * 16));
        sacc[ts] = mfma32(ka, qf[hh], sacc[ts]);
      }
    }
    __builtin_amdgcn_s_setprio(0);
    #pragma unroll
    for (int ts = 0; ts < 2; ++ts)
      #pragma unroll
      for (int r = 0; r < 16; ++r) { float p = exp2f(sacc[ts][r]); sacc[ts][r] = p; lsum += p; }

    #pragma unroll
    for (int m = 0; m < 4; ++m) {
      const int ts = m >> 1, rb = 8*(m & 1);
      const unsigned A0 = pk2f(sacc[ts][rb+0], sacc[ts][rb+1]);
      const unsigned A1 = pk2f(sacc[ts][rb+2], sacc[ts][rb+3]);
      const unsigned B0 = pk2f(sacc[ts][rb+4], sacc[ts][rb+5]);
      const unsigned B1 = pk2f(sacc[ts][rb+6], sacc[ts][rb+7]);
      const unsigned s0 = hi ? A0 : B0;
      const unsigned s1 = hi ? A1 : B1;
      const unsigned r0 = __shfl_xor(s0, 32);
      const unsigned r1 = __shfl_xor(s1, 32);
      union { unsigned u[4]; s16x8 v; } fr;
      fr.u[0] = hi ? r0 : A0;  fr.u[1] = hi ? r1 : A1;
      fr.u[2] = hi ? B0 : r0;  fr.u[3] = hi ? B1 : r1;
      __builtin_amdgcn_s_setprio(1);
      #pragma unroll
      for (int dt = 0; dt < 2; ++dt) {
        const int drow = dt*32 + qm;
        s16x8 va = *reinterpret_cast<const s16x8*>(
            smem + bb + 8192 + drow*128 + (((2*m + hi) ^ l7) * 16));
        oacc[dt] = mfma32(va, fr.v, oacc[dt]);
      }
      __builtin_amdgcn_s_setprio(0);
    }
  };

  stage(0, 0);
  __syncthreads();
  for (int kt = 0; kt < 16; kt += 2) {
    stage(16384, kt + 1);
    compute(0);
    __syncthreads();
    if (kt + 2 < 16) stage(0, kt + 2);
    compute(16384);
    __syncthreads();
  }

  lsum += __shfl_xor(lsum, 32);
  const float inv = 1.0f / lsum;

  const int qloc = w*32 + qm;
  #pragma unroll
  for (int dt = 0; dt < 2; ++dt)
    #pragma unroll
    for (int rq = 0; rq < 4; ++rq) {
      const unsigned u0 = pk2f(oacc[dt][rq*4+0]*inv, oacc[dt][rq*4+1]*inv);
      const unsigned u1 = pk2f(oacc[dt][rq*4+2]*inv, oacc[dt][rq*4+3]*inv);
      const unsigned long long v = ((unsigned long long)u1 << 32) | u0;
      *reinterpret_cast<unsigned long long*>(
          smem + qloc*128 + (((4*dt + rq) ^ (qm & 7)) * 16) + 8*hi) = v;
    }
  __syncthreads();
  {
    const int qr = t >> 1, half = t & 1;
    char* dst = (char*)ao + ((size_t)(b*Tn + qt*128 + qr))*(Cn*2) + (h*Dn + half*32)*2;
    #pragma unroll
    for (int sl = 0; sl < 4; ++sl) {
      uint4 v = *reinterpret_cast<const uint4*>(
          smem + qr*128 + (((half*4 + sl) ^ (qr & 7)) * 16));
      *reinterpret_cast<uint4*>(dst + sl*16) = v;
    }
  }
}

// ---------- output projection + bias: BK=64, 2-phase dbuf ----------
__global__ __launch_bounds__(256) void out_proj(
    const __hip_bfloat16* __restrict__ ab, const __hip_bfloat16* __restrict__ wpb,
    const float* __restrict__ bp, float* __restrict__ out)
{
  __shared__ __align__(16) char sm[32768];
  const int t = threadIdx.x, lane = t & 63, w = t >> 6;
  const int hi = lane >> 5, nl = lane & 31;
  const int wr = w >> 1, wc = w & 1;
  const int m0 = blockIdx.x * 64;
  const int n0 = blockIdx.y * 64;

  const int mrow = wr*32 + nl;
  const int nrow = wc*32 + nl;
  f32x16 acc = {};

  auto stage = [&](int bb, int s) {
    #pragma unroll
    for (int c = 0; c < 4; ++c) {
      const int off = w*4096 + c*1024 + lane*16;
      const char* src;
      if (off < 8192) {
        const int row = off >> 7, sl = (off >> 4) & 7;
        src = (const char*)ab + (size_t)(m0 + row)*768 + s*128 + ((sl ^ (row & 7)) * 16);
      } else {
        const int o2 = off - 8192;
        const int row = o2 >> 7, sl = (o2 >> 4) & 7;
        src = (const char*)wpb + (size_t)(n0 + row)*768 + s*128 + ((sl ^ (row & 7)) * 16);
      }
      gl_lds16(src, sm + bb + w*4096 + c*1024);
    }
  };
  auto compute = [&](int bb) {
    __builtin_amdgcn_s_setprio(1);
    #pragma unroll
    for (int kk = 0; kk < 4; ++kk) {
      s16x8 a  = *reinterpret_cast<const s16x8*>(sm + bb + mrow*128 + (((2*kk + hi) ^ (mrow & 7)) * 16));
      s16x8 bv = *reinterpret_cast<const s16x8*>(sm + bb + 8192 + nrow*128 + (((2*kk + hi) ^ (nrow & 7)) * 16));
      acc = mfma32(a, bv, acc);
    }
    __builtin_amdgcn_s_setprio(0);
  };

  stage(0, 0);
  __syncthreads();
  for (int s = 0; s < 6; s += 2) {
    stage(16384, s + 1);
    compute(0);
    __syncthreads();
    if (s + 2 < 6) stage(0, s + 2);
    compute(16384);
    __syncthreads();
  }

  const int n = n0 + wc*32 + nl;
  const float bv = bp[n];
  #pragma unroll
  for (int r = 0; r < 16; ++r) {
    const int ml = wr*32 + (r & 3) + 8*(r >> 2) + 4*hi;
    out[(size_t)(m0 + ml)*Cn + n] = acc[r] + bv;
  }
}

extern "C" void kernel_launch(void* const* d_in, const int* in_sizes, int n_in,
                              void* d_out, int out_size, void* d_ws, size_t ws_size,
                              hipStream_t stream) {
  const float* x  = (const float*)d_in[0];
  const float* wq = (const float*)d_in[1];
  const float* wk = (const float*)d_in[2];
  const float* wv = (const float*)d_in[3];
  const float* wp = (const float*)d_in[4];
  const float* bp = (const float*)d_in[5];
  float* out = (float*)d_out;

  unsigned char* W = (unsigned char*)d_ws;
  __hip_bfloat16* wt  = (__hip_bfloat16*)(W);               //    884,736 B  [3][H][D][C]
  __hip_bfloat16* wpb = (__hip_bfloat16*)(W + 884736);      //    294,912 B
  __hip_bfloat16* qv  = (__hip_bfloat16*)(W + 1179648);     // 12,582,912 B
  __hip_bfloat16* kv  = (__hip_bfloat16*)(W + 13762560);    // 12,582,912 B
  __hip_bfloat16* vt  = (__hip_bfloat16*)(W + 26345472);    // 12,582,912 B
  __hip_bfloat16* at  = (__hip_bfloat16*)(W + 38928384);    // 12,582,912 B -> ends 51,511,296

  convert_w<<<90, 256, 0, stream>>>(wq, wk, wv, wp, wt, wpb);
  qkv_proj<<<dim3(Mn/64, 3), 256, 0, stream>>>(x, wt, qv, kv, vt);
  attn_fwd<<<Bn*Hn*(Tn/128), 256, 0, stream>>>(qv, kv, vt, at);
  out_proj<<<dim3(Mn/64, Cn/64), 256, 0, stream>>>(at, wpb, bp, out);
}

// Round 10
// 171.096 us; speedup vs baseline: 1.1340x; 1.1340x over previous
//
#include <hip/hip_runtime.h>
#include <hip/hip_bf16.h>

// MHA B=16 T=1024 C=384 H=6 D=64 — bf16 MFMA pipeline.
// R10: R6 structure; attn uses raw v_exp_f32 + v_cvt_pk_bf16_f32 (VALU-instruction diet).
#define Hn 6
#define Tn 1024
#define Cn 384
#define Dn 64
#define Bn 16
#define Mn (Bn*Tn)
#define QSCALE 0.07362222f   // log2(e)/sqrt(384): folds softmax scale + exp2 conversion into wq

typedef __attribute__((ext_vector_type(8)))  short s16x8;
typedef __attribute__((ext_vector_type(16))) float f32x16;

__device__ __forceinline__ void gl_lds16(const void* g, void* l) {
  __builtin_amdgcn_global_load_lds(
      (const __attribute__((address_space(1))) unsigned int*)g,
      (__attribute__((address_space(3))) unsigned int*)l, 16, 0, 0);
}
__device__ __forceinline__ unsigned pk2f(float a, float b) {
  __hip_bfloat162 h = __float22bfloat162_rn(make_float2(a, b));
  union { __hip_bfloat162 h; unsigned u; } cv; cv.h = h; return cv.u;
}
__device__ __forceinline__ unsigned cvtpk(float a, float b) {   // lo=a, hi=b (RNE)
  unsigned r;
  asm("v_cvt_pk_bf16_f32 %0, %1, %2" : "=v"(r) : "v"(a), "v"(b));
  return r;
}
__device__ __forceinline__ f32x16 mfma32(s16x8 a, s16x8 b, f32x16 c) {
  return __builtin_amdgcn_mfma_f32_32x32x16_bf16(a, b, c, 0, 0, 0);
}

// ---------- convert: x->bf16; w -> bf16 transposed [mat][h][d][c] (wq scaled); wp->bf16 ----------
__global__ __launch_bounds__(256) void convert_all(
    const float* __restrict__ x, const float* __restrict__ wq,
    const float* __restrict__ wk, const float* __restrict__ wv,
    const float* __restrict__ wp,
    __hip_bfloat16* __restrict__ xb, __hip_bfloat16* __restrict__ wt,
    __hip_bfloat16* __restrict__ wpb)
{
  const int bid = blockIdx.x, t = threadIdx.x;
  if (bid < 18) {                       // weight transpose, one (mat,h) per block
    __shared__ float lt[64][65];
    const int mat = bid / Hn, hh = bid % Hn;
    const float* src = (mat == 0 ? wq : mat == 1 ? wk : wv) + (size_t)hh * (Cn*Dn);
    __hip_bfloat16* dst = wt + (size_t)mat * (Hn*Dn*Cn) + (size_t)hh * (Dn*Cn);
    const float sc = (mat == 0) ? QSCALE : 1.0f;
    for (int ct = 0; ct < 6; ++ct) {    // 6 c-tiles of 64
      __syncthreads();
      #pragma unroll
      for (int ps = 0; ps < 4; ++ps) {
        int idx = ps*256 + t;
        int cl = idx >> 4, s4 = idx & 15;
        float4 v = *reinterpret_cast<const float4*>(src + (size_t)(ct*64 + cl)*Dn + s4*4);
        lt[cl][s4*4+0] = v.x * sc; lt[cl][s4*4+1] = v.y * sc;
        lt[cl][s4*4+2] = v.z * sc; lt[cl][s4*4+3] = v.w * sc;
      }
      __syncthreads();
      const int dd = t >> 2, cq = t & 3;
      #pragma unroll
      for (int i = 0; i < 16; ++i)
        dst[(size_t)dd*Cn + ct*64 + cq*16 + i] = __float2bfloat16(lt[cq*16 + i][dd]);
    }
  } else if (bid < 90) {                // wp copy (no transpose: B-operand wants [j][i] rows)
    const size_t base = (size_t)(bid - 18) * 2048 + (size_t)t * 8;
    float4 a = *reinterpret_cast<const float4*>(wp + base);
    float4 b = *reinterpret_cast<const float4*>(wp + base + 4);
    uint4 r; r.x = pk2f(a.x,a.y); r.y = pk2f(a.z,a.w); r.z = pk2f(b.x,b.y); r.w = pk2f(b.z,b.w);
    *reinterpret_cast<uint4*>((char*)wpb + base*2) = r;
  } else {                              // x -> bf16
    const size_t base = (size_t)(bid - 90) * 2048 + (size_t)t * 8;
    float4 a = *reinterpret_cast<const float4*>(x + base);
    float4 b = *reinterpret_cast<const float4*>(x + base + 4);
    uint4 r; r.x = pk2f(a.x,a.y); r.y = pk2f(a.z,a.w); r.z = pk2f(b.x,b.y); r.w = pk2f(b.z,b.w);
    *reinterpret_cast<uint4*>((char*)xb + base*2) = r;
  }
}

// ---------- qkv projection: 64x64 tile, BK=64, 2-phase dbuf, mfma 32x32x16 ----------
__global__ __launch_bounds__(256) void qkv_proj(
    const __hip_bfloat16* __restrict__ xb, const __hip_bfloat16* __restrict__ wt,
    __hip_bfloat16* __restrict__ qo, __hip_bfloat16* __restrict__ ko,
    __hip_bfloat16* __restrict__ vto)
{
  __shared__ __align__(16) char sm[32768];  // 2 x (X[64][64] | W[64][64]), slot16 ^ (row&7)
  const int t = threadIdx.x, lane = t & 63, w = t >> 6;
  const int hi = lane >> 5, nl = lane & 31;
  const int wr = w >> 1, wc = w & 1;
  const int m0 = blockIdx.x * 64;
  const int mat = blockIdx.y / Hn, h = blockIdx.y % Hn;
  const __hip_bfloat16* wb = wt + (size_t)mat*(Hn*Dn*Cn) + (size_t)h*(Dn*Cn);

  const int mrow = wr*32 + nl;
  const int nrow = wc*32 + nl;
  f32x16 acc = {};

  auto stage = [&](int bb, int s) {       // stage k-step s (k0 = s*64) into buffer bb
    #pragma unroll
    for (int c = 0; c < 4; ++c) {
      const int off = w*4096 + c*1024 + lane*16;
      const char* src;
      if (off < 8192) {
        const int row = off >> 7, sl = (off >> 4) & 7;
        src = (const char*)xb + (size_t)(m0 + row)*768 + s*128 + ((sl ^ (row & 7)) * 16);
      } else {
        const int o2 = off - 8192;
        const int row = o2 >> 7, sl = (o2 >> 4) & 7;
        src = (const char*)wb + (size_t)row*768 + s*128 + ((sl ^ (row & 7)) * 16);
      }
      gl_lds16(src, sm + bb + w*4096 + c*1024);
    }
  };
  auto compute = [&](int bb) {
    __builtin_amdgcn_s_setprio(1);
    #pragma unroll
    for (int kk = 0; kk < 4; ++kk) {
      s16x8 a  = *reinterpret_cast<const s16x8*>(sm + bb + mrow*128 + (((2*kk + hi) ^ (mrow & 7)) * 16));
      s16x8 bv = *reinterpret_cast<const s16x8*>(sm + bb + 8192 + nrow*128 + (((2*kk + hi) ^ (nrow & 7)) * 16));
      acc = mfma32(a, bv, acc);
    }
    __builtin_amdgcn_s_setprio(0);
  };

  stage(0, 0);
  __syncthreads();
  for (int s = 0; s < 6; s += 2) {
    stage(16384, s + 1);
    compute(0);
    __syncthreads();
    if (s + 2 < 6) stage(0, s + 2);
    compute(16384);
    __syncthreads();
  }

  // C layout: col = nl, row = (r&3)+8*(r>>2)+4*hi  [m74/m101]
  const int d = wc*32 + nl;
  if (mat < 2) {
    __hip_bfloat16* op = (mat == 0) ? qo : ko;
    #pragma unroll
    for (int r = 0; r < 16; ++r) {
      const int ml = wr*32 + (r & 3) + 8*(r >> 2) + 4*hi;
      const int M = m0 + ml, bI = M >> 10, tl = M & 1023;
      op[(((size_t)bI*Hn + h)*Tn + tl)*Dn + d] = __float2bfloat16(acc[r]);
    }
  } else {                               // V transposed: vto[b,h,d,t]
    #pragma unroll
    for (int rq = 0; rq < 4; ++rq) {
      const int ml = wr*32 + 8*rq + 4*hi;
      const int M = m0 + ml, bI = M >> 10, tl = M & 1023;
      const unsigned u0 = pk2f(acc[rq*4+0], acc[rq*4+1]);
      const unsigned u1 = pk2f(acc[rq*4+2], acc[rq*4+3]);
      const unsigned long long v = ((unsigned long long)u1 << 32) | u0;
      *reinterpret_cast<unsigned long long*>(
          (char*)vto + ((((size_t)bI*Hn + h)*Dn + d)*Tn + tl)*2) = v;
    }
  }
}

// ---------- attention: QB=128 (4 waves x 32q), KV tiles 64, dbuf, swapped QK^T, no max-sub ----------
// Block swizzle: bh = bx%96, qt = bx/96 -> the 8 qt-blocks of one (b,h) share an XCD (96%8==0).
__global__ __launch_bounds__(256) void attn_fwd(
    const __hip_bfloat16* __restrict__ qb, const __hip_bfloat16* __restrict__ kb,
    const __hip_bfloat16* __restrict__ vtb, __hip_bfloat16* __restrict__ ao)
{
  __shared__ __align__(16) char smem[32768];   // 2 x (K[64][64] | VT[64][64]), slot16 ^ (row&7)
  const int t = threadIdx.x, lane = t & 63, w = t >> 6;
  const int hi = lane >> 5, qm = lane & 31;
  const int l7 = lane & 7;
  const int bx = blockIdx.x;
  const int bh = bx % 96, qt = bx / 96;        // XCD-grouping swizzle
  const int b = bh / Hn, h = bh % Hn;

  const int qrow = qt*128 + w*32 + qm;
  const __hip_bfloat16* qrp = qb + ((size_t)bh*Tn + qrow)*Dn;
  s16x8 qf[4];
  #pragma unroll
  for (int hh = 0; hh < 4; ++hh)
    qf[hh] = *reinterpret_cast<const s16x8*>(qrp + hh*16 + hi*8);

  const size_t kbase = (size_t)bh * Tn * Dn;
  const size_t vbase = (size_t)bh * Dn * Tn;

  f32x16 oacc[2] = {};
  float lsum = 0.f;

  auto stage = [&](int bb, int kt) {
    #pragma unroll
    for (int c = 0; c < 4; ++c) {
      const int off = w*4096 + c*1024 + lane*16;
      const char* src;
      if (off < 8192) {
        const int row = off >> 7, sl = (off >> 4) & 7;
        src = (const char*)(kb + kbase + (size_t)(kt*64 + row)*Dn) + ((sl ^ (row & 7)) * 16);
      } else {
        const int o2 = off - 8192;
        const int row = o2 >> 7, sl = (o2 >> 4) & 7;
        src = (const char*)(vtb + vbase + (size_t)row*Tn + kt*64) + ((sl ^ (row & 7)) * 16);
      }
      gl_lds16(src, smem + bb + w*4096 + c*1024);
    }
  };

  auto compute = [&](int bb) {
    f32x16 sacc[2] = {};
    __builtin_amdgcn_s_setprio(1);
    #pragma unroll
    for (int ts = 0; ts < 2; ++ts) {
      const int srow = ts*32 + qm;
      #pragma unroll
      for (int hh = 0; hh < 4; ++hh) {
        s16x8 ka = *reinterpret_cast<const s16x8*>(
            smem + bb + srow*128 + (((2*hh + hi) ^ l7) * 16));
        sacc[ts] = mfma32(ka, qf[hh], sacc[ts]);
      }
    }
    __builtin_amdgcn_s_setprio(0);
    // p = exp2(s) via raw v_exp_f32 (scale folded into Q); accumulate denominator
    #pragma unroll
    for (int ts = 0; ts < 2; ++ts)
      #pragma unroll
      for (int r = 0; r < 16; ++r) {
        float p = __builtin_amdgcn_exp2f(sacc[ts][r]);
        sacc[ts][r] = p; lsum += p;
      }

    // build P^T B-frags (k = s = 16m+8hi+j) via one cross-half exchange per m; PV mfma
    #pragma unroll
    for (int m = 0; m < 4; ++m) {
      const int ts = m >> 1, rb = 8*(m & 1);
      const unsigned A0 = cvtpk(sacc[ts][rb+0], sacc[ts][rb+1]);
      const unsigned A1 = cvtpk(sacc[ts][rb+2], sacc[ts][rb+3]);
      const unsigned B0 = cvtpk(sacc[ts][rb+4], sacc[ts][rb+5]);
      const unsigned B1 = cvtpk(sacc[ts][rb+6], sacc[ts][rb+7]);
      const unsigned s0 = hi ? A0 : B0;      // send what the partner half needs
      const unsigned s1 = hi ? A1 : B1;
      const unsigned r0 = __shfl_xor(s0, 32);
      const unsigned r1 = __shfl_xor(s1, 32);
      union { unsigned u[4]; s16x8 v; } fr;
      fr.u[0] = hi ? r0 : A0;  fr.u[1] = hi ? r1 : A1;
      fr.u[2] = hi ? B0 : r0;  fr.u[3] = hi ? B1 : r1;
      __builtin_amdgcn_s_setprio(1);
      #pragma unroll
      for (int dt = 0; dt < 2; ++dt) {
        const int drow = dt*32 + qm;
        s16x8 va = *reinterpret_cast<const s16x8*>(
            smem + bb + 8192 + drow*128 + (((2*m + hi) ^ l7) * 16));
        oacc[dt] = mfma32(va, fr.v, oacc[dt]);
      }
      __builtin_amdgcn_s_setprio(0);
    }
  };

  stage(0, 0);
  __syncthreads();
  for (int kt = 0; kt < 16; kt += 2) {
    stage(16384, kt + 1);
    compute(0);
    __syncthreads();
    if (kt + 2 < 16) stage(0, kt + 2);
    compute(16384);
    __syncthreads();
  }

  lsum += __shfl_xor(lsum, 32);
  const float inv = 1.0f / lsum;

  // epilogue: OT -> LDS (swizzled, reuse buf0) -> coalesced bf16 rows of att[M][C]
  const int qloc = w*32 + qm;
  #pragma unroll
  for (int dt = 0; dt < 2; ++dt)
    #pragma unroll
    for (int rq = 0; rq < 4; ++rq) {
      const unsigned u0 = cvtpk(oacc[dt][rq*4+0]*inv, oacc[dt][rq*4+1]*inv);
      const unsigned u1 = cvtpk(oacc[dt][rq*4+2]*inv, oacc[dt][rq*4+3]*inv);
      const unsigned long long v = ((unsigned long long)u1 << 32) | u0;
      *reinterpret_cast<unsigned long long*>(
          smem + qloc*128 + (((4*dt + rq) ^ (qm & 7)) * 16) + 8*hi) = v;
    }
  __syncthreads();
  {
    const int qr = t >> 1, half = t & 1;
    char* dst = (char*)ao + ((size_t)(b*Tn + qt*128 + qr))*(Cn*2) + (h*Dn + half*32)*2;
    #pragma unroll
    for (int sl = 0; sl < 4; ++sl) {
      uint4 v = *reinterpret_cast<const uint4*>(
          smem + qr*128 + (((half*4 + sl) ^ (qr & 7)) * 16));
      *reinterpret_cast<uint4*>(dst + sl*16) = v;
    }
  }
}

// ---------- output projection + bias: BK=64, 2-phase dbuf ----------
__global__ __launch_bounds__(256) void out_proj(
    const __hip_bfloat16* __restrict__ ab, const __hip_bfloat16* __restrict__ wpb,
    const float* __restrict__ bp, float* __restrict__ out)
{
  __shared__ __align__(16) char sm[32768];
  const int t = threadIdx.x, lane = t & 63, w = t >> 6;
  const int hi = lane >> 5, nl = lane & 31;
  const int wr = w >> 1, wc = w & 1;
  const int m0 = blockIdx.x * 64;
  const int n0 = blockIdx.y * 64;

  const int mrow = wr*32 + nl;
  const int nrow = wc*32 + nl;
  f32x16 acc = {};

  auto stage = [&](int bb, int s) {
    #pragma unroll
    for (int c = 0; c < 4; ++c) {
      const int off = w*4096 + c*1024 + lane*16;
      const char* src;
      if (off < 8192) {
        const int row = off >> 7, sl = (off >> 4) & 7;
        src = (const char*)ab + (size_t)(m0 + row)*768 + s*128 + ((sl ^ (row & 7)) * 16);
      } else {
        const int o2 = off - 8192;
        const int row = o2 >> 7, sl = (o2 >> 4) & 7;
        src = (const char*)wpb + (size_t)(n0 + row)*768 + s*128 + ((sl ^ (row & 7)) * 16);
      }
      gl_lds16(src, sm + bb + w*4096 + c*1024);
    }
  };
  auto compute = [&](int bb) {
    __builtin_amdgcn_s_setprio(1);
    #pragma unroll
    for (int kk = 0; kk < 4; ++kk) {
      s16x8 a  = *reinterpret_cast<const s16x8*>(sm + bb + mrow*128 + (((2*kk + hi) ^ (mrow & 7)) * 16));
      s16x8 bv = *reinterpret_cast<const s16x8*>(sm + bb + 8192 + nrow*128 + (((2*kk + hi) ^ (nrow & 7)) * 16));
      acc = mfma32(a, bv, acc);
    }
    __builtin_amdgcn_s_setprio(0);
  };

  stage(0, 0);
  __syncthreads();
  for (int s = 0; s < 6; s += 2) {
    stage(16384, s + 1);
    compute(0);
    __syncthreads();
    if (s + 2 < 6) stage(0, s + 2);
    compute(16384);
    __syncthreads();
  }

  const int n = n0 + wc*32 + nl;
  const float bv = bp[n];
  #pragma unroll
  for (int r = 0; r < 16; ++r) {
    const int ml = wr*32 + (r & 3) + 8*(r >> 2) + 4*hi;
    out[(size_t)(m0 + ml)*Cn + n] = acc[r] + bv;
  }
}

extern "C" void kernel_launch(void* const* d_in, const int* in_sizes, int n_in,
                              void* d_out, int out_size, void* d_ws, size_t ws_size,
                              hipStream_t stream) {
  const float* x  = (const float*)d_in[0];
  const float* wq = (const float*)d_in[1];
  const float* wk = (const float*)d_in[2];
  const float* wv = (const float*)d_in[3];
  const float* wp = (const float*)d_in[4];
  const float* bp = (const float*)d_in[5];
  float* out = (float*)d_out;

  unsigned char* W = (unsigned char*)d_ws;
  __hip_bfloat16* xb  = (__hip_bfloat16*)(W);               // 12,582,912 B
  __hip_bfloat16* wt  = (__hip_bfloat16*)(W + 12582912);    //    884,736 B  [3][H][D][C]
  __hip_bfloat16* wpb = (__hip_bfloat16*)(W + 13467648);    //    294,912 B
  __hip_bfloat16* qv  = (__hip_bfloat16*)(W + 13762560);    // 12,582,912 B
  __hip_bfloat16* kv  = (__hip_bfloat16*)(W + 26345472);    // 12,582,912 B
  __hip_bfloat16* vt  = (__hip_bfloat16*)(W + 38928384);    // 12,582,912 B
  __hip_bfloat16* at  = (__hip_bfloat16*)(W + 51511296);    // 12,582,912 B -> ends 64,094,208

  convert_all<<<3162, 256, 0, stream>>>(x, wq, wk, wv, wp, xb, wt, wpb);
  qkv_proj<<<dim3(Mn/64, 3*Hn), 256, 0, stream>>>(xb, wt, qv, kv, vt);
  attn_fwd<<<Bn*Hn*(Tn/128), 256, 0, stream>>>(qv, kv, vt, at);
  out_proj<<<dim3(Mn/64, Cn/64), 256, 0, stream>>>(at, wpb, bp, out);
}